// Round 4
// baseline (1150.304 us; speedup 1.0000x reference)
//
#include <hip/hip_runtime.h>

#define NNODES 50000
#define NEDGES 800000
#define F 128
#define NREL 8
#define NOUT 1152   // 9*128: 8 relations + self-loop
#define NBKT 98     // ceil(50000 / 512) coarse buckets
#define BSH 9       // 512 nodes per bucket
#define SEG 16384   // fixed ebuf segment per bucket (max bucket ~8.5k)
#define NTILES 391  // ceil(50000/128)
#define GEMM_BLOCKS (8 * 9 * 49)   // 3528 (XCD-swizzled)
#define CSR_BLOCKS 196

typedef short bf16x8 __attribute__((ext_vector_type(8)));
typedef float f32x4 __attribute__((ext_vector_type(4)));
typedef float f32x2 __attribute__((ext_vector_type(2)));

__device__ __forceinline__ unsigned f2bf(float f) {  // RNE
  unsigned u = __float_as_uint(f);
  u += 0x7fffu + ((u >> 16) & 1u);
  return u >> 16;
}
__device__ __forceinline__ float bf2f(unsigned v) {
  return __uint_as_float(v << 16);
}

typedef __attribute__((address_space(3))) void lds_void;
typedef const __attribute__((address_space(1))) void glb_void;
__device__ __forceinline__ void gll16(const void* g, void* l) {
  // async global->LDS, 16B per lane; LDS dest = wave-uniform base + lane*16
  __builtin_amdgcn_global_load_lds(
      (glb_void*)(unsigned long long)g,
      (lds_void*)(unsigned)(unsigned long long)l, 16, 0, 0);
}

// ========== fused prep: zero | cvt | prepw(W1) | prepw(W2) ==================
// R18: chist deleted (bucket counts come from bcur after the csr scatter);
// memset dispatch deleted (blocks [0,33) zero pooled_p / bcur / donecnt).
#define PREP_ZERO  33
#define PREP_CVT   12500   // 50000*128/2 / 256
#define PREP_W     576     // 1152*128 / 256
__global__ __launch_bounds__(256)
void k_prep(const float* __restrict__ in_feat, ushort* __restrict__ feat0,
            const float* __restrict__ W1, const float* __restrict__ W1s,
            ushort* __restrict__ Wt1,
            const float* __restrict__ W2, const float* __restrict__ W2s,
            ushort* __restrict__ Wt2,
            float* __restrict__ pooled_p, int* __restrict__ bcur) {
  const int b = blockIdx.x, t = threadIdx.x;
  if (b < 32) {
    pooled_p[b * 256 + t] = 0.f;          // 32*256 = 8192 = 64*128
  } else if (b < PREP_ZERO) {
    if (t <= NBKT) bcur[t] = 0;           // bcur[98] + donecnt
  } else if (b < PREP_ZERO + PREP_CVT) {
    int i = (b - PREP_ZERO) * 256 + t;    // exactly 3.2M
    float2 v = ((const float2*)in_feat)[i];
    ((unsigned*)feat0)[i] = f2bf(v.x) | (f2bf(v.y) << 16);
  } else {
    int w2 = (b >= PREP_ZERO + PREP_CVT + PREP_W);
    int idx = (b - PREP_ZERO - PREP_CVT - (w2 ? PREP_W : 0)) * 256 + t;
    int n = idx >> 7, k = idx & 127;
    int r = n >> 7, c = n & 127;
    const float* Wr = w2 ? W2 : W1;
    const float* Ws = w2 ? W2s : W1s;
    float v = (r < NREL) ? Wr[((size_t)r * F + k) * F + c] : Ws[(size_t)k * F + c];
    (w2 ? Wt2 : Wt1)[idx] = (ushort)f2bf(v);
  }
}

// ======== fine sort: bucket segment -> CSR (counts from bcur) ===============
__global__ __launch_bounds__(256)
void k_fsort(const int* __restrict__ ebuf, const int* __restrict__ bcur,
             int* __restrict__ rowptr, int* __restrict__ edata) {
  __shared__ int cnt[512];
  __shared__ int pos[512];
  __shared__ int ws2[256];
  __shared__ int bc_s;
  const int b = blockIdx.x, t = threadIdx.x;
  // ---- global base = sum_{k<b} bcur[k] (bcur holds final bucket counts) ----
  int myc = (t < NBKT) ? bcur[t] : 0;
  ws2[t] = (t < b) ? myc : 0;
  if (t == b) bc_s = myc;
  __syncthreads();
  for (int off = 1; off < 256; off <<= 1) {
    int x = (t >= off) ? ws2[t - off] : 0;
    __syncthreads();
    ws2[t] += x;
    __syncthreads();
  }
  const int beg = ws2[255];
  const int cntb = bc_s;
  const int sbeg = b * SEG;  // segment start in ebuf

  cnt[t] = 0; cnt[t + 256] = 0;
  __syncthreads();
  for (int e = t; e < cntb; e += 256)
    atomicAdd(&cnt[((unsigned)ebuf[sbeg + e]) >> 19], 1);
  __syncthreads();
  int a = cnt[2 * t], b2 = cnt[2 * t + 1];
  ws2[t] = a + b2;
  __syncthreads();
  for (int off = 1; off < 256; off <<= 1) {
    int x = (t >= off) ? ws2[t - off] : 0;
    __syncthreads();
    ws2[t] += x;
    __syncthreads();
  }
  int ep = ws2[t] - (a + b2);
  pos[2 * t] = ep;
  pos[2 * t + 1] = ep + a;
  __syncthreads();
  int node0 = b << BSH;
#pragma unroll
  for (int i = t; i < 512; i += 256) {
    int node = node0 + i;
    if (node < NNODES) rowptr[node] = beg + pos[i];
  }
  if (b == NBKT - 1 && t == 0) rowptr[NNODES] = NEDGES;
  __syncthreads();
  for (int e = t; e < cntb; e += 256) {
    int rec = ebuf[sbeg + e];
    int c = ((unsigned)rec) >> 19;
    int lrank = atomicAdd(&pos[c], 1);
    int srcv = (rec >> 3) & 0xFFFF;
    int etv = rec & 7;
    edata[beg + lrank] = srcv * NOUT + etv * F;  // byte offset in fp8 xrs
  }
}

// ====== GEMM: xrs[50000][1152](fp8) = A[50000][128] @ Wt^T  (bf16 MFMA) =====
// R14 structure (proven): full-K, one barrier, XOR-swizzled 64KB LDS,
// 512 threads / 8 waves (32x64 each). R16: epilogue LDS-transpose stores
// (8x128B segments per wave-instr). R17: staging via global_load_lds
// (linear LDS dest + pre-swizzled source, rule 21) - no VGPR round-trip.
// doCsr: blocks [0,196) instead run the coarse CSR scatter (fixed-stride
// segments, bucket-local counters; bcur ends at the exact bucket counts,
// consumed by k_fsort - no separate histogram pass).
__global__ __launch_bounds__(512, 4)
void gemm_xrs(const ushort* __restrict__ A, const ushort* __restrict__ Wt,
              unsigned char* __restrict__ xrs, int doCsr,
              const int* __restrict__ src, const int* __restrict__ dst,
              const int* __restrict__ et, int* __restrict__ bcur,
              int* __restrict__ ebuf) {
  __shared__ uint4 As[2048];  // 128 rows x 16 uint4, xor-swizzled
  __shared__ uint4 Bs[2048];
  __shared__ int lhist[NBKT];
  __shared__ int lbase[NBKT];
  const int tid = threadIdx.x;

  if (doCsr && blockIdx.x < CSR_BLOCKS) {
    // ---- coarse scatter: record = (dst_local<<19)|(src<<3)|et ----
    if (tid < NBKT) lhist[tid] = 0;
    __syncthreads();
    int e0 = blockIdx.x * 4096;
    int rec[8], cc[8], lr[8];
#pragma unroll
    for (int i = 0; i < 8; ++i) {
      int e = e0 + tid + i * 512;
      if (e < NEDGES) {
        int d = dst[e];
        cc[i] = d >> BSH;
        rec[i] = ((d & 511) << 19) | (src[e] << 3) | et[e];
        lr[i] = atomicAdd(&lhist[cc[i]], 1);
      } else {
        cc[i] = -1;
      }
    }
    __syncthreads();
    if (tid < NBKT && lhist[tid] > 0) lbase[tid] = atomicAdd(&bcur[tid], lhist[tid]);
    __syncthreads();
#pragma unroll
    for (int i = 0; i < 8; ++i)
      if (cc[i] >= 0) ebuf[cc[i] * SEG + lbase[cc[i]] + lr[i]] = rec[i];
    return;
  }

  const int id = blockIdx.x - (doCsr ? CSR_BLOCKS : 0);
  const int x = id & 7, j = id >> 3;
  const int tile = (j / 9) * 8 + x;
  const int cb = j % 9;
  if (tile >= NTILES) return;
  const int row0 = tile * 128;

  const int lane = tid & 63;
  const int w = tid >> 6;           // 0..7
  const int i16 = lane & 15, q = lane >> 4;
  const int mbase = (w & 3) * 32, nbase = (w >> 2) * 64;

  // Stage full tiles via global_load_lds: linear LDS dest slot L receives
  // source column (L&15) ^ (r&15)  (same XOR involution as the read side).
#pragma unroll
  for (int i = 0; i < 4; ++i) {
    int L = tid + i * 512;
    int r = L >> 4, c4s = L & 15;
    int c4 = c4s ^ (r & 15);
    int agr = row0 + r; if (agr >= NNODES) agr = NNODES - 1;
    gll16((const void*)(A + (size_t)agr * F + c4 * 8), (void*)&As[L]);
    gll16((const void*)(Wt + ((size_t)cb * 128 + r) * F + c4 * 8), (void*)&Bs[L]);
  }
  __syncthreads();

  f32x4 acc[2][4];
#pragma unroll
  for (int a = 0; a < 2; ++a)
#pragma unroll
    for (int b = 0; b < 4; ++b) acc[a][b] = (f32x4)0.f;

#pragma unroll
  for (int c = 0; c < 4; ++c) {
    bf16x8 af[2], bfr[4];
#pragma unroll
    for (int mi = 0; mi < 2; ++mi) {
      int r = mbase + mi * 16 + i16;
      af[mi] = *(const bf16x8*)&As[r * 16 + ((c * 4 + q) ^ (r & 15))];
    }
#pragma unroll
    for (int ni = 0; ni < 4; ++ni) {
      int r = nbase + ni * 16 + i16;
      bfr[ni] = *(const bf16x8*)&Bs[r * 16 + ((c * 4 + q) ^ (r & 15))];
    }
    // Swapped operands: D[m=weight feature][n=node row]
#pragma unroll
    for (int mi = 0; mi < 2; ++mi)
#pragma unroll
      for (int ni = 0; ni < 4; ++ni)
        acc[mi][ni] = __builtin_amdgcn_mfma_f32_16x16x32_bf16(
            bfr[ni], af[mi], acc[mi][ni], 0, 0, 0);
  }

  // ---- Epilogue with LDS transpose (R16) ----
  // Pack fp8 dwords (bit-identical), stage into swizzled sbuf[nl][32], then
  // store cooperatively: 8 lanes x 16B = one node's contiguous 128B slice.
  unsigned pkv[2][4];
#pragma unroll
  for (int mi = 0; mi < 2; ++mi)
#pragma unroll
    for (int ni = 0; ni < 4; ++ni) {
      f32x4 v = acc[mi][ni];
      unsigned pk = 0;
      pk = __builtin_amdgcn_cvt_pk_fp8_f32(v[0], v[1], pk, false);
      pk = __builtin_amdgcn_cvt_pk_fp8_f32(v[2], v[3], pk, true);
      pkv[mi][ni] = pk;
    }

  __syncthreads();  // all waves done reading As/Bs; reuse As as staging
  unsigned* sbuf = (unsigned*)As;  // [128 nodes][32 dwords] = 16KB
  {
    const int dbase = (nbase >> 2) + q;
#pragma unroll
    for (int mi = 0; mi < 2; ++mi) {
      int nl = mbase + mi * 16 + i16;
      int sw = (nl & 7) << 2;
      int vb_ = nl * 32;
#pragma unroll
      for (int ni = 0; ni < 4; ++ni)
        sbuf[vb_ + ((dbase + ni * 4) ^ sw)] = pkv[mi][ni];
    }
  }
  __syncthreads();

#pragma unroll
  for (int k = 0; k < 2; ++k) {
    int nl = k * 64 + (tid >> 3);
    int ch = tid & 7;
    int d0 = (ch * 4) ^ ((nl & 7) << 2);
    uint4 v = *(const uint4*)&sbuf[nl * 32 + d0];
    int row = row0 + nl;
    if (row < NNODES)
      *(uint4*)(xrs + (size_t)row * NOUT + cb * 128 + ch * 16) = v;
  }
}

// ========== aggregate: h_next[dst] = relu(sum_e xrs[edata] + self + b) ======
// Paired-edge: half-wave (32 lanes) per edge, 4B dword loads, 8 pairs in
// flight, __shfl for offsets, __shfl_xor(32) merges halves. 12500 blocks x
// 4 nodes = 50000 exactly. hout != null: store bf16 h. pooled_p != null:
// LDS-reduce block's 4 nodes, atomicAdd into 64-slot-spread partials, and
// (R18) the LAST block to finish reduces partials + fc + sigmoid (fused
// k_final via donecnt last-block pattern).
__global__ __launch_bounds__(256)
void k_aggregate(const unsigned char* __restrict__ xrs,
                 const int* __restrict__ rowptr, const int* __restrict__ edata,
                 const float* __restrict__ bias, ushort* __restrict__ hout,
                 float* __restrict__ pooled_p, int* __restrict__ donecnt,
                 const float* __restrict__ fcw, const float* __restrict__ fcb,
                 float* __restrict__ out) {
  __shared__ float red[4][128];
  const int wv = threadIdx.x >> 6;
  const int node = blockIdx.x * 4 + wv;
  const int lane = threadIdx.x & 63;
  const int half = lane >> 5, sl = lane & 31;
  const int beg = rowptr[node], end = rowptr[node + 1];

  float a0 = 0.f, a1 = 0.f, a2 = 0.f, a3 = 0.f;
  // self-loop row (r=8), counted once by half 0
  if (half == 0) {
    unsigned sv = *(const unsigned*)(xrs + (size_t)node * NOUT + NREL * F + sl * 4);
    f32x2 lo = __builtin_amdgcn_cvt_pk_f32_fp8(sv, false);
    f32x2 hi = __builtin_amdgcn_cvt_pk_f32_fp8(sv, true);
    a0 += lo[0]; a1 += lo[1]; a2 += hi[0]; a3 += hi[1];
  }

  for (int base = beg; base < end; base += 64) {
    int cnt = end - base; if (cnt > 64) cnt = 64;
    int my = (base + lane < end) ? edata[base + lane] : 0;
    int pairs = cnt >> 1;
    int p = 0;
    for (; p + 8 <= pairs; p += 8) {
      unsigned v[8];
#pragma unroll
      for (int k = 0; k < 8; ++k) {
        int off = __shfl(my, 2 * (p + k) + half, 64);
        v[k] = *(const unsigned*)(xrs + (size_t)off + sl * 4);
      }
#pragma unroll
      for (int k = 0; k < 8; ++k) {
        f32x2 lo = __builtin_amdgcn_cvt_pk_f32_fp8(v[k], false);
        f32x2 hi = __builtin_amdgcn_cvt_pk_f32_fp8(v[k], true);
        a0 += lo[0]; a1 += lo[1]; a2 += hi[0]; a3 += hi[1];
      }
    }
    for (; p < pairs; ++p) {
      int off = __shfl(my, 2 * p + half, 64);
      unsigned vv = *(const unsigned*)(xrs + (size_t)off + sl * 4);
      f32x2 lo = __builtin_amdgcn_cvt_pk_f32_fp8(vv, false);
      f32x2 hi = __builtin_amdgcn_cvt_pk_f32_fp8(vv, true);
      a0 += lo[0]; a1 += lo[1]; a2 += hi[0]; a3 += hi[1];
    }
    if (cnt & 1) {
      int off = __shfl(my, cnt - 1, 64);
      if (half == 0) {
        unsigned vv = *(const unsigned*)(xrs + (size_t)off + sl * 4);
        f32x2 lo = __builtin_amdgcn_cvt_pk_f32_fp8(vv, false);
        f32x2 hi = __builtin_amdgcn_cvt_pk_f32_fp8(vv, true);
        a0 += lo[0]; a1 += lo[1]; a2 += hi[0]; a3 += hi[1];
      }
    }
  }

  // merge the two half-wave partial sums
  a0 += __shfl_xor(a0, 32, 64);
  a1 += __shfl_xor(a1, 32, 64);
  a2 += __shfl_xor(a2, 32, 64);
  a3 += __shfl_xor(a3, 32, 64);

  float4 bb = ((const float4*)bias)[sl];
  a0 = fmaxf(a0 + bb.x, 0.f);
  a1 = fmaxf(a1 + bb.y, 0.f);
  a2 = fmaxf(a2 + bb.z, 0.f);
  a3 = fmaxf(a3 + bb.w, 0.f);

  if (hout) {
    if (half == 0) {
      uint2 pk;
      pk.x = f2bf(a0) | (f2bf(a1) << 16);
      pk.y = f2bf(a2) | (f2bf(a3) << 16);
      ((uint2*)(hout + (size_t)node * F))[sl] = pk;
    }
    return;
  }

  // ---- pooled path: per-block reduce + spread atomics ----
  if (half == 0) {
    red[wv][sl * 4 + 0] = a0;
    red[wv][sl * 4 + 1] = a1;
    red[wv][sl * 4 + 2] = a2;
    red[wv][sl * 4 + 3] = a3;
  }
  __syncthreads();
  if (threadIdx.x < 128) {
    float s = red[0][threadIdx.x] + red[1][threadIdx.x] +
              red[2][threadIdx.x] + red[3][threadIdx.x];
    atomicAdd(&pooled_p[(blockIdx.x & 63) * 128 + threadIdx.x], s);
  }

  // ---- fused final (R18): last block reduces partials + fc + sigmoid ----
  __shared__ int lastFlag;
  __threadfence();  // flush this block's pooled_p atomics to device scope
  if (threadIdx.x == 0)
    lastFlag = (atomicAdd(donecnt, 1) == (int)gridDim.x - 1);
  __syncthreads();
  if (!lastFlag) return;
  __threadfence();  // acquire: all other blocks' atomics now visible

  float* s = &red[0][0];  // reuse LDS
  const int t = threadIdx.x;
  if (t < 128) {
    float acc = 0.f;
#pragma unroll 8
    for (int k = 0; k < 64; ++k) acc += pooled_p[k * 128 + t];
    s[t] = acc * (1.0f / (float)NNODES) * fcw[t];
  }
  __syncthreads();
  if (t == 0) {
    float v = 0.f;
    for (int i = 0; i < 128; ++i) v += s[i];
    v += fcb[0];
    out[0] = 1.f / (1.f + expf(-v));
  }
}

// ============================================================================
extern "C" void kernel_launch(void* const* d_in, const int* in_sizes, int n_in,
                              void* d_out, int out_size, void* d_ws, size_t ws_size,
                              hipStream_t stream) {
  const float* in_feat = (const float*)d_in[0];
  const float* W1      = (const float*)d_in[1];
  const float* W1s     = (const float*)d_in[2];
  const float* b1      = (const float*)d_in[3];
  const float* W2      = (const float*)d_in[4];
  const float* W2s     = (const float*)d_in[5];
  const float* b2      = (const float*)d_in[6];
  const float* fcw     = (const float*)d_in[7];
  const float* fcb     = (const float*)d_in[8];
  const int*   src     = (const int*)d_in[9];
  const int*   dst     = (const int*)d_in[10];
  const int*   et      = (const int*)d_in[11];
  float* out = (float*)d_out;

  // Workspace (~100 MB)
  unsigned char* xrs = (unsigned char*)d_ws;              // [50000][1152] fp8
  ushort* feat0 = (ushort*)(xrs + (size_t)NNODES * NOUT); // [50000][128] bf16
  ushort* h1    = feat0 + (size_t)NNODES * F;             // [50000][128]
  ushort* Wt1   = h1 + (size_t)NNODES * F;                // [1152][128]
  ushort* Wt2   = Wt1 + (size_t)NOUT * F;                 // [1152][128]
  float* pooled_p = (float*)(Wt2 + (size_t)NOUT * F);     // [64][128]
  int*   bcur   = (int*)(pooled_p + 64 * 128);            // [NBKT]
  int*   donecnt= bcur + NBKT;                            // [1]
  int*   rowptr = donecnt + 1;                            // [NNODES+1]
  int*   ebuf   = rowptr + NNODES + 2;                    // [NBKT*SEG]
  int*   edata  = ebuf + NBKT * SEG;                      // [NEDGES]

  // fused prep: zero(pooled_p,bcur,donecnt) | feat cvt | weight prep x2
  k_prep<<<PREP_ZERO + PREP_CVT + 2 * PREP_W, 256, 0, stream>>>(
      in_feat, feat0, W1, W1s, Wt1, W2, W2s, Wt2, pooled_p, bcur);

  const int aggBlocks = NNODES / 4;                    // 12500

  // Layer 1 GEMM with CSR-scatter fused (scatter hidden under GEMM)
  gemm_xrs<<<CSR_BLOCKS + GEMM_BLOCKS, 512, 0, stream>>>(
      feat0, Wt1, xrs, 1, src, dst, et, bcur, ebuf);
  k_fsort<<<NBKT, 256, 0, stream>>>(ebuf, bcur, rowptr, edata);
  k_aggregate<<<aggBlocks, 256, 0, stream>>>(
      xrs, rowptr, edata, b1, h1, nullptr, nullptr, nullptr, nullptr, nullptr);
  // Layer 2 (pooling + final fc fused into aggregate; h2 never materialized)
  gemm_xrs<<<GEMM_BLOCKS, 512, 0, stream>>>(
      h1, Wt2, xrs, 0, src, dst, et, bcur, ebuf);
  k_aggregate<<<aggBlocks, 256, 0, stream>>>(
      xrs, rowptr, edata, b2, nullptr, pooled_p, donecnt, fcw, fcb, out);
}

// Round 5
// 231.757 us; speedup vs baseline: 4.9634x; 4.9634x over previous
//
#include <hip/hip_runtime.h>

#define NNODES 50000
#define NEDGES 800000
#define F 128
#define NREL 8
#define NOUT 1152   // 9*128: 8 relations + self-loop
#define NBKT 98     // ceil(50000 / 512) coarse buckets
#define BSH 9       // 512 nodes per bucket
#define SEG 16384   // fixed ebuf segment per bucket (max bucket ~8.5k)
#define NTILES 391  // ceil(50000/128)
#define GEMM_BLOCKS (8 * 9 * 49)   // 3528 (XCD-swizzled)
#define CSR_BLOCKS 196

typedef short bf16x8 __attribute__((ext_vector_type(8)));
typedef float f32x4 __attribute__((ext_vector_type(4)));
typedef float f32x2 __attribute__((ext_vector_type(2)));

__device__ __forceinline__ unsigned f2bf(float f) {  // RNE
  unsigned u = __float_as_uint(f);
  u += 0x7fffu + ((u >> 16) & 1u);
  return u >> 16;
}
__device__ __forceinline__ float bf2f(unsigned v) {
  return __uint_as_float(v << 16);
}

typedef __attribute__((address_space(3))) void lds_void;
typedef const __attribute__((address_space(1))) void glb_void;
__device__ __forceinline__ void gll16(const void* g, void* l) {
  // async global->LDS, 16B per lane; LDS dest = wave-uniform base + lane*16
  __builtin_amdgcn_global_load_lds(
      (glb_void*)(unsigned long long)g,
      (lds_void*)(unsigned)(unsigned long long)l, 16, 0, 0);
}

// ========== fused prep: zero | cvt | prepw(W1) | prepw(W2) ==================
// R18: chist deleted (bucket counts come from bcur after the csr scatter);
// memset dispatch deleted (blocks [0,33) zero pooled_p / bcur).
#define PREP_ZERO  33
#define PREP_CVT   12500   // 50000*128/2 / 256
#define PREP_W     576     // 1152*128 / 256
__global__ __launch_bounds__(256)
void k_prep(const float* __restrict__ in_feat, ushort* __restrict__ feat0,
            const float* __restrict__ W1, const float* __restrict__ W1s,
            ushort* __restrict__ Wt1,
            const float* __restrict__ W2, const float* __restrict__ W2s,
            ushort* __restrict__ Wt2,
            float* __restrict__ pooled_p, int* __restrict__ bcur) {
  const int b = blockIdx.x, t = threadIdx.x;
  if (b < 32) {
    pooled_p[b * 256 + t] = 0.f;          // 32*256 = 8192 = 64*128
  } else if (b < PREP_ZERO) {
    if (t <= NBKT) bcur[t] = 0;           // bcur[98] (+1 spare)
  } else if (b < PREP_ZERO + PREP_CVT) {
    int i = (b - PREP_ZERO) * 256 + t;    // exactly 3.2M
    float2 v = ((const float2*)in_feat)[i];
    ((unsigned*)feat0)[i] = f2bf(v.x) | (f2bf(v.y) << 16);
  } else {
    int w2 = (b >= PREP_ZERO + PREP_CVT + PREP_W);
    int idx = (b - PREP_ZERO - PREP_CVT - (w2 ? PREP_W : 0)) * 256 + t;
    int n = idx >> 7, k = idx & 127;
    int r = n >> 7, c = n & 127;
    const float* Wr = w2 ? W2 : W1;
    const float* Ws = w2 ? W2s : W1s;
    float v = (r < NREL) ? Wr[((size_t)r * F + k) * F + c] : Ws[(size_t)k * F + c];
    (w2 ? Wt2 : Wt1)[idx] = (ushort)f2bf(v);
  }
}

// ======== fine sort: bucket segment -> CSR (counts from bcur) ===============
__global__ __launch_bounds__(256)
void k_fsort(const int* __restrict__ ebuf, const int* __restrict__ bcur,
             int* __restrict__ rowptr, int* __restrict__ edata) {
  __shared__ int cnt[512];
  __shared__ int pos[512];
  __shared__ int ws2[256];
  __shared__ int bc_s;
  const int b = blockIdx.x, t = threadIdx.x;
  // ---- global base = sum_{k<b} bcur[k] (bcur holds final bucket counts) ----
  int myc = (t < NBKT) ? bcur[t] : 0;
  ws2[t] = (t < b) ? myc : 0;
  if (t == b) bc_s = myc;
  __syncthreads();
  for (int off = 1; off < 256; off <<= 1) {
    int x = (t >= off) ? ws2[t - off] : 0;
    __syncthreads();
    ws2[t] += x;
    __syncthreads();
  }
  const int beg = ws2[255];
  const int cntb = bc_s;
  const int sbeg = b * SEG;  // segment start in ebuf

  cnt[t] = 0; cnt[t + 256] = 0;
  __syncthreads();
  for (int e = t; e < cntb; e += 256)
    atomicAdd(&cnt[((unsigned)ebuf[sbeg + e]) >> 19], 1);
  __syncthreads();
  int a = cnt[2 * t], b2 = cnt[2 * t + 1];
  ws2[t] = a + b2;
  __syncthreads();
  for (int off = 1; off < 256; off <<= 1) {
    int x = (t >= off) ? ws2[t - off] : 0;
    __syncthreads();
    ws2[t] += x;
    __syncthreads();
  }
  int ep = ws2[t] - (a + b2);
  pos[2 * t] = ep;
  pos[2 * t + 1] = ep + a;
  __syncthreads();
  int node0 = b << BSH;
#pragma unroll
  for (int i = t; i < 512; i += 256) {
    int node = node0 + i;
    if (node < NNODES) rowptr[node] = beg + pos[i];
  }
  if (b == NBKT - 1 && t == 0) rowptr[NNODES] = NEDGES;
  __syncthreads();
  for (int e = t; e < cntb; e += 256) {
    int rec = ebuf[sbeg + e];
    int c = ((unsigned)rec) >> 19;
    int lrank = atomicAdd(&pos[c], 1);
    int srcv = (rec >> 3) & 0xFFFF;
    int etv = rec & 7;
    edata[beg + lrank] = srcv * NOUT + etv * F;  // byte offset in fp8 xrs
  }
}

// ====== GEMM: xrs[50000][1152](fp8) = A[50000][128] @ Wt^T  (bf16 MFMA) =====
// R14 structure (proven): full-K, one barrier, XOR-swizzled 64KB LDS,
// 512 threads / 8 waves (32x64 each). R16: epilogue LDS-transpose stores
// (8x128B segments per wave-instr). R17: staging via global_load_lds
// (linear LDS dest + pre-swizzled source, rule 21) - no VGPR round-trip.
// doCsr: blocks [0,196) instead run the coarse CSR scatter (fixed-stride
// segments, bucket-local counters; bcur ends at the exact bucket counts,
// consumed by k_fsort - no separate histogram pass).
__global__ __launch_bounds__(512, 4)
void gemm_xrs(const ushort* __restrict__ A, const ushort* __restrict__ Wt,
              unsigned char* __restrict__ xrs, int doCsr,
              const int* __restrict__ src, const int* __restrict__ dst,
              const int* __restrict__ et, int* __restrict__ bcur,
              int* __restrict__ ebuf) {
  __shared__ uint4 As[2048];  // 128 rows x 16 uint4, xor-swizzled
  __shared__ uint4 Bs[2048];
  __shared__ int lhist[NBKT];
  __shared__ int lbase[NBKT];
  const int tid = threadIdx.x;

  if (doCsr && blockIdx.x < CSR_BLOCKS) {
    // ---- coarse scatter: record = (dst_local<<19)|(src<<3)|et ----
    if (tid < NBKT) lhist[tid] = 0;
    __syncthreads();
    int e0 = blockIdx.x * 4096;
    int rec[8], cc[8], lr[8];
#pragma unroll
    for (int i = 0; i < 8; ++i) {
      int e = e0 + tid + i * 512;
      if (e < NEDGES) {
        int d = dst[e];
        cc[i] = d >> BSH;
        rec[i] = ((d & 511) << 19) | (src[e] << 3) | et[e];
        lr[i] = atomicAdd(&lhist[cc[i]], 1);
      } else {
        cc[i] = -1;
      }
    }
    __syncthreads();
    if (tid < NBKT && lhist[tid] > 0) lbase[tid] = atomicAdd(&bcur[tid], lhist[tid]);
    __syncthreads();
#pragma unroll
    for (int i = 0; i < 8; ++i)
      if (cc[i] >= 0) ebuf[cc[i] * SEG + lbase[cc[i]] + lr[i]] = rec[i];
    return;
  }

  const int id = blockIdx.x - (doCsr ? CSR_BLOCKS : 0);
  const int x = id & 7, j = id >> 3;
  const int tile = (j / 9) * 8 + x;
  const int cb = j % 9;
  if (tile >= NTILES) return;
  const int row0 = tile * 128;

  const int lane = tid & 63;
  const int w = tid >> 6;           // 0..7
  const int i16 = lane & 15, q = lane >> 4;
  const int mbase = (w & 3) * 32, nbase = (w >> 2) * 64;

  // Stage full tiles via global_load_lds: linear LDS dest slot L receives
  // source column (L&15) ^ (r&15)  (same XOR involution as the read side).
#pragma unroll
  for (int i = 0; i < 4; ++i) {
    int L = tid + i * 512;
    int r = L >> 4, c4s = L & 15;
    int c4 = c4s ^ (r & 15);
    int agr = row0 + r; if (agr >= NNODES) agr = NNODES - 1;
    gll16((const void*)(A + (size_t)agr * F + c4 * 8), (void*)&As[L]);
    gll16((const void*)(Wt + ((size_t)cb * 128 + r) * F + c4 * 8), (void*)&Bs[L]);
  }
  __syncthreads();

  f32x4 acc[2][4];
#pragma unroll
  for (int a = 0; a < 2; ++a)
#pragma unroll
    for (int b = 0; b < 4; ++b) acc[a][b] = (f32x4)0.f;

#pragma unroll
  for (int c = 0; c < 4; ++c) {
    bf16x8 af[2], bfr[4];
#pragma unroll
    for (int mi = 0; mi < 2; ++mi) {
      int r = mbase + mi * 16 + i16;
      af[mi] = *(const bf16x8*)&As[r * 16 + ((c * 4 + q) ^ (r & 15))];
    }
#pragma unroll
    for (int ni = 0; ni < 4; ++ni) {
      int r = nbase + ni * 16 + i16;
      bfr[ni] = *(const bf16x8*)&Bs[r * 16 + ((c * 4 + q) ^ (r & 15))];
    }
    // Swapped operands: D[m=weight feature][n=node row]
#pragma unroll
    for (int mi = 0; mi < 2; ++mi)
#pragma unroll
      for (int ni = 0; ni < 4; ++ni)
        acc[mi][ni] = __builtin_amdgcn_mfma_f32_16x16x32_bf16(
            bfr[ni], af[mi], acc[mi][ni], 0, 0, 0);
  }

  // ---- Epilogue with LDS transpose (R16) ----
  // Pack fp8 dwords (bit-identical), stage into swizzled sbuf[nl][32], then
  // store cooperatively: 8 lanes x 16B = one node's contiguous 128B slice.
  unsigned pkv[2][4];
#pragma unroll
  for (int mi = 0; mi < 2; ++mi)
#pragma unroll
    for (int ni = 0; ni < 4; ++ni) {
      f32x4 v = acc[mi][ni];
      unsigned pk = 0;
      pk = __builtin_amdgcn_cvt_pk_fp8_f32(v[0], v[1], pk, false);
      pk = __builtin_amdgcn_cvt_pk_fp8_f32(v[2], v[3], pk, true);
      pkv[mi][ni] = pk;
    }

  __syncthreads();  // all waves done reading As/Bs; reuse As as staging
  unsigned* sbuf = (unsigned*)As;  // [128 nodes][32 dwords] = 16KB
  {
    const int dbase = (nbase >> 2) + q;
#pragma unroll
    for (int mi = 0; mi < 2; ++mi) {
      int nl = mbase + mi * 16 + i16;
      int sw = (nl & 7) << 2;
      int vb_ = nl * 32;
#pragma unroll
      for (int ni = 0; ni < 4; ++ni)
        sbuf[vb_ + ((dbase + ni * 4) ^ sw)] = pkv[mi][ni];
    }
  }
  __syncthreads();

#pragma unroll
  for (int k = 0; k < 2; ++k) {
    int nl = k * 64 + (tid >> 3);
    int ch = tid & 7;
    int d0 = (ch * 4) ^ ((nl & 7) << 2);
    uint4 v = *(const uint4*)&sbuf[nl * 32 + d0];
    int row = row0 + nl;
    if (row < NNODES)
      *(uint4*)(xrs + (size_t)row * NOUT + cb * 128 + ch * 16) = v;
  }
}

// ========== aggregate: h_next[dst] = relu(sum_e xrs[edata] + self + b) ======
// Paired-edge: half-wave (32 lanes) per edge, 4B dword loads, 8 pairs in
// flight, __shfl for offsets, __shfl_xor(32) merges halves. 12500 blocks x
// 4 nodes = 50000 exactly. hout != null: store bf16 h. pooled_p != null:
// LDS-reduce block's 4 nodes, atomicAdd into 64-slot-spread partials.
// R19: fused-final REVERTED (12500x __threadfence = L2-writeback storm,
// 960us measured in R18). k_final is a separate dispatch again.
__global__ __launch_bounds__(256)
void k_aggregate(const unsigned char* __restrict__ xrs,
                 const int* __restrict__ rowptr, const int* __restrict__ edata,
                 const float* __restrict__ bias, ushort* __restrict__ hout,
                 float* __restrict__ pooled_p) {
  __shared__ float red[4][128];
  const int wv = threadIdx.x >> 6;
  const int node = blockIdx.x * 4 + wv;
  const int lane = threadIdx.x & 63;
  const int half = lane >> 5, sl = lane & 31;
  const int beg = rowptr[node], end = rowptr[node + 1];

  float a0 = 0.f, a1 = 0.f, a2 = 0.f, a3 = 0.f;
  // self-loop row (r=8), counted once by half 0
  if (half == 0) {
    unsigned sv = *(const unsigned*)(xrs + (size_t)node * NOUT + NREL * F + sl * 4);
    f32x2 lo = __builtin_amdgcn_cvt_pk_f32_fp8(sv, false);
    f32x2 hi = __builtin_amdgcn_cvt_pk_f32_fp8(sv, true);
    a0 += lo[0]; a1 += lo[1]; a2 += hi[0]; a3 += hi[1];
  }

  for (int base = beg; base < end; base += 64) {
    int cnt = end - base; if (cnt > 64) cnt = 64;
    int my = (base + lane < end) ? edata[base + lane] : 0;
    int pairs = cnt >> 1;
    int p = 0;
    for (; p + 8 <= pairs; p += 8) {
      unsigned v[8];
#pragma unroll
      for (int k = 0; k < 8; ++k) {
        int off = __shfl(my, 2 * (p + k) + half, 64);
        v[k] = *(const unsigned*)(xrs + (size_t)off + sl * 4);
      }
#pragma unroll
      for (int k = 0; k < 8; ++k) {
        f32x2 lo = __builtin_amdgcn_cvt_pk_f32_fp8(v[k], false);
        f32x2 hi = __builtin_amdgcn_cvt_pk_f32_fp8(v[k], true);
        a0 += lo[0]; a1 += lo[1]; a2 += hi[0]; a3 += hi[1];
      }
    }
    for (; p < pairs; ++p) {
      int off = __shfl(my, 2 * p + half, 64);
      unsigned vv = *(const unsigned*)(xrs + (size_t)off + sl * 4);
      f32x2 lo = __builtin_amdgcn_cvt_pk_f32_fp8(vv, false);
      f32x2 hi = __builtin_amdgcn_cvt_pk_f32_fp8(vv, true);
      a0 += lo[0]; a1 += lo[1]; a2 += hi[0]; a3 += hi[1];
    }
    if (cnt & 1) {
      int off = __shfl(my, cnt - 1, 64);
      if (half == 0) {
        unsigned vv = *(const unsigned*)(xrs + (size_t)off + sl * 4);
        f32x2 lo = __builtin_amdgcn_cvt_pk_f32_fp8(vv, false);
        f32x2 hi = __builtin_amdgcn_cvt_pk_f32_fp8(vv, true);
        a0 += lo[0]; a1 += lo[1]; a2 += hi[0]; a3 += hi[1];
      }
    }
  }

  // merge the two half-wave partial sums
  a0 += __shfl_xor(a0, 32, 64);
  a1 += __shfl_xor(a1, 32, 64);
  a2 += __shfl_xor(a2, 32, 64);
  a3 += __shfl_xor(a3, 32, 64);

  float4 bb = ((const float4*)bias)[sl];
  a0 = fmaxf(a0 + bb.x, 0.f);
  a1 = fmaxf(a1 + bb.y, 0.f);
  a2 = fmaxf(a2 + bb.z, 0.f);
  a3 = fmaxf(a3 + bb.w, 0.f);

  if (hout) {
    if (half == 0) {
      uint2 pk;
      pk.x = f2bf(a0) | (f2bf(a1) << 16);
      pk.y = f2bf(a2) | (f2bf(a3) << 16);
      ((uint2*)(hout + (size_t)node * F))[sl] = pk;
    }
  } else {
    if (half == 0) {
      red[wv][sl * 4 + 0] = a0;
      red[wv][sl * 4 + 1] = a1;
      red[wv][sl * 4 + 2] = a2;
      red[wv][sl * 4 + 3] = a3;
    }
    __syncthreads();
    if (threadIdx.x < 128) {
      float s = red[0][threadIdx.x] + red[1][threadIdx.x] +
                red[2][threadIdx.x] + red[3][threadIdx.x];
      atomicAdd(&pooled_p[(blockIdx.x & 63) * 128 + threadIdx.x], s);
    }
  }
}

// ================== final: reduce 64x128 partials + fc + sigmoid ============
__global__ __launch_bounds__(128)
void k_final(const float* __restrict__ pooled_p, const float* __restrict__ fcw,
             const float* __restrict__ fcb, float* __restrict__ out) {
  __shared__ float s[128];
  int t = threadIdx.x;
  float acc = 0.f;
#pragma unroll 8
  for (int k = 0; k < 64; ++k) acc += pooled_p[k * 128 + t];
  s[t] = acc * (1.0f / (float)NNODES) * fcw[t];
  __syncthreads();
  if (t == 0) {
    float v = 0.f;
    for (int i = 0; i < 128; ++i) v += s[i];
    v += fcb[0];
    out[0] = 1.f / (1.f + expf(-v));
  }
}

// ============================================================================
extern "C" void kernel_launch(void* const* d_in, const int* in_sizes, int n_in,
                              void* d_out, int out_size, void* d_ws, size_t ws_size,
                              hipStream_t stream) {
  const float* in_feat = (const float*)d_in[0];
  const float* W1      = (const float*)d_in[1];
  const float* W1s     = (const float*)d_in[2];
  const float* b1      = (const float*)d_in[3];
  const float* W2      = (const float*)d_in[4];
  const float* W2s     = (const float*)d_in[5];
  const float* b2      = (const float*)d_in[6];
  const float* fcw     = (const float*)d_in[7];
  const float* fcb     = (const float*)d_in[8];
  const int*   src     = (const int*)d_in[9];
  const int*   dst     = (const int*)d_in[10];
  const int*   et      = (const int*)d_in[11];
  float* out = (float*)d_out;

  // Workspace (~100 MB)
  unsigned char* xrs = (unsigned char*)d_ws;              // [50000][1152] fp8
  ushort* feat0 = (ushort*)(xrs + (size_t)NNODES * NOUT); // [50000][128] bf16
  ushort* h1    = feat0 + (size_t)NNODES * F;             // [50000][128]
  ushort* Wt1   = h1 + (size_t)NNODES * F;                // [1152][128]
  ushort* Wt2   = Wt1 + (size_t)NOUT * F;                 // [1152][128]
  float* pooled_p = (float*)(Wt2 + (size_t)NOUT * F);     // [64][128]
  int*   bcur   = (int*)(pooled_p + 64 * 128);            // [NBKT+1]
  int*   rowptr = bcur + NBKT + 1;                        // [NNODES+1]
  int*   ebuf   = rowptr + NNODES + 2;                    // [NBKT*SEG]
  int*   edata  = ebuf + NBKT * SEG;                      // [NEDGES]

  // fused prep: zero(pooled_p,bcur) | feat cvt | weight prep x2
  k_prep<<<PREP_ZERO + PREP_CVT + 2 * PREP_W, 256, 0, stream>>>(
      in_feat, feat0, W1, W1s, Wt1, W2, W2s, Wt2, pooled_p, bcur);

  const int aggBlocks = NNODES / 4;                    // 12500

  // Layer 1 GEMM with CSR-scatter fused (scatter hidden under GEMM)
  gemm_xrs<<<CSR_BLOCKS + GEMM_BLOCKS, 512, 0, stream>>>(
      feat0, Wt1, xrs, 1, src, dst, et, bcur, ebuf);
  k_fsort<<<NBKT, 256, 0, stream>>>(ebuf, bcur, rowptr, edata);
  k_aggregate<<<aggBlocks, 256, 0, stream>>>(xrs, rowptr, edata, b1, h1, nullptr);
  // Layer 2 (pooling fused into aggregate; h2 never materialized)
  gemm_xrs<<<GEMM_BLOCKS, 512, 0, stream>>>(
      h1, Wt2, xrs, 0, src, dst, et, bcur, ebuf);
  k_aggregate<<<aggBlocks, 256, 0, stream>>>(xrs, rowptr, edata, b2, nullptr, pooled_p);

  // Reduce partials + fc + sigmoid
  k_final<<<1, 128, 0, stream>>>(pooled_p, fcw, fcb, out);
}

// Round 6
// 220.076 us; speedup vs baseline: 5.2268x; 1.0531x over previous
//
#include <hip/hip_runtime.h>

#define NNODES 50000
#define NEDGES 800000
#define F 128
#define NREL 8
#define NOUT 1152   // 9*128: 8 relations + self-loop
#define NBKT 98     // ceil(50000 / 512) coarse buckets
#define BSH 9       // 512 nodes per bucket
#define SEG 16384   // fixed ebuf segment per bucket (max bucket ~8.5k)
#define NTILES 391  // ceil(50000/128)
#define GEMM_BLOCKS (8 * 9 * 49)   // 3528 (XCD-swizzled)
#define CSR_BLOCKS 196

typedef float f32x4 __attribute__((ext_vector_type(4)));
typedef float f32x2 __attribute__((ext_vector_type(2)));

__device__ __forceinline__ unsigned f2bf(float f) {  // RNE
  unsigned u = __float_as_uint(f);
  u += 0x7fffu + ((u >> 16) & 1u);
  return u >> 16;
}

typedef __attribute__((address_space(3))) void lds_void;
typedef const __attribute__((address_space(1))) void glb_void;
__device__ __forceinline__ void gll16(const void* g, void* l) {
  // async global->LDS, 16B per lane; LDS dest = wave-uniform base + lane*16
  __builtin_amdgcn_global_load_lds(
      (glb_void*)(unsigned long long)g,
      (lds_void*)(unsigned)(unsigned long long)l, 16, 0, 0);
}

// ========== fused prep: zero | cvt(fp8) | prepw(W1) | prepw(W2) =============
// R20: feat0 and Wt are fp8 e4m3 now (GEMM datapath is fp8 end-to-end).
#define PREP_ZERO  33
#define PREP_CVT   6250    // 50000*128/4 / 256 uints
#define PREP_W     144     // 1152*128/4 / 256 uints per weight set
__global__ __launch_bounds__(256)
void k_prep(const float* __restrict__ in_feat, unsigned* __restrict__ feat0,
            const float* __restrict__ W1, const float* __restrict__ W1s,
            unsigned* __restrict__ Wt1,
            const float* __restrict__ W2, const float* __restrict__ W2s,
            unsigned* __restrict__ Wt2,
            float* __restrict__ pooled_p, int* __restrict__ bcur) {
  const int b = blockIdx.x, t = threadIdx.x;
  if (b < 32) {
    pooled_p[b * 256 + t] = 0.f;          // 32*256 = 8192 = 64*128
  } else if (b < PREP_ZERO) {
    if (t <= NBKT) bcur[t] = 0;           // bcur[98] (+1 spare)
  } else if (b < PREP_ZERO + PREP_CVT) {
    int i = (b - PREP_ZERO) * 256 + t;    // exactly 1.6M float4 -> uint
    float4 v = ((const float4*)in_feat)[i];
    unsigned pk = 0;
    pk = __builtin_amdgcn_cvt_pk_fp8_f32(v.x, v.y, pk, false);
    pk = __builtin_amdgcn_cvt_pk_fp8_f32(v.z, v.w, pk, true);
    feat0[i] = pk;
  } else {
    int w2 = (b >= PREP_ZERO + PREP_CVT + PREP_W);
    int idx = (b - PREP_ZERO - PREP_CVT - (w2 ? PREP_W : 0)) * 256 + t;
    int n = idx >> 5, k0 = (idx & 31) * 4;   // Wt[n][k0..k0+3]
    int r = n >> 7, c = n & 127;
    const float* Wr = w2 ? W2 : W1;
    const float* Ws = w2 ? W2s : W1s;
    float v0, v1, v2, v3;
    if (r < NREL) {
      v0 = Wr[((size_t)(r * F + k0 + 0)) * F + c];
      v1 = Wr[((size_t)(r * F + k0 + 1)) * F + c];
      v2 = Wr[((size_t)(r * F + k0 + 2)) * F + c];
      v3 = Wr[((size_t)(r * F + k0 + 3)) * F + c];
    } else {
      v0 = Ws[(size_t)(k0 + 0) * F + c];
      v1 = Ws[(size_t)(k0 + 1) * F + c];
      v2 = Ws[(size_t)(k0 + 2) * F + c];
      v3 = Ws[(size_t)(k0 + 3) * F + c];
    }
    unsigned pk = 0;
    pk = __builtin_amdgcn_cvt_pk_fp8_f32(v0, v1, pk, false);
    pk = __builtin_amdgcn_cvt_pk_fp8_f32(v2, v3, pk, true);
    (w2 ? Wt2 : Wt1)[idx] = pk;
  }
}

// ======== fine sort: bucket segment -> CSR (counts from bcur) ===============
__global__ __launch_bounds__(256)
void k_fsort(const int* __restrict__ ebuf, const int* __restrict__ bcur,
             int* __restrict__ rowptr, int* __restrict__ edata) {
  __shared__ int cnt[512];
  __shared__ int pos[512];
  __shared__ int ws2[256];
  __shared__ int bc_s;
  const int b = blockIdx.x, t = threadIdx.x;
  // ---- global base = sum_{k<b} bcur[k] (bcur holds final bucket counts) ----
  int myc = (t < NBKT) ? bcur[t] : 0;
  ws2[t] = (t < b) ? myc : 0;
  if (t == b) bc_s = myc;
  __syncthreads();
  for (int off = 1; off < 256; off <<= 1) {
    int x = (t >= off) ? ws2[t - off] : 0;
    __syncthreads();
    ws2[t] += x;
    __syncthreads();
  }
  const int beg = ws2[255];
  const int cntb = bc_s;
  const int sbeg = b * SEG;  // segment start in ebuf

  cnt[t] = 0; cnt[t + 256] = 0;
  __syncthreads();
  for (int e = t; e < cntb; e += 256)
    atomicAdd(&cnt[((unsigned)ebuf[sbeg + e]) >> 19], 1);
  __syncthreads();
  int a = cnt[2 * t], b2 = cnt[2 * t + 1];
  ws2[t] = a + b2;
  __syncthreads();
  for (int off = 1; off < 256; off <<= 1) {
    int x = (t >= off) ? ws2[t - off] : 0;
    __syncthreads();
    ws2[t] += x;
    __syncthreads();
  }
  int ep = ws2[t] - (a + b2);
  pos[2 * t] = ep;
  pos[2 * t + 1] = ep + a;
  __syncthreads();
  int node0 = b << BSH;
#pragma unroll
  for (int i = t; i < 512; i += 256) {
    int node = node0 + i;
    if (node < NNODES) rowptr[node] = beg + pos[i];
  }
  if (b == NBKT - 1 && t == 0) rowptr[NNODES] = NEDGES;
  __syncthreads();
  for (int e = t; e < cntb; e += 256) {
    int rec = ebuf[sbeg + e];
    int c = ((unsigned)rec) >> 19;
    int lrank = atomicAdd(&pos[c], 1);
    int srcv = (rec >> 3) & 0xFFFF;
    int etv = rec & 7;
    edata[beg + lrank] = srcv * NOUT + etv * F;  // byte offset in fp8 xrs
  }
}

// ====== GEMM: xrs[50000][1152](fp8) = A[50000][128] @ Wt^T  (fp8 MFMA) ======
// R20: full fp8 datapath. As/Bs 16KB each (LDS 33.5KB -> 4 blocks/CU,
// launch_bounds(512,8)). Staging 2 gll16/thread/buffer (half of R17).
// 8B-granular XOR swizzle: slot L holds source 16B-chunk (L&7)^(r&7);
// ds_read_b64 frag reads land 2 lanes/bank (free). mfma_f32_16x16x32_fp8_fp8
// with swapped operands keeps the same C/D layout (dtype-independent).
// Epilogue LDS-transpose stores unchanged (sbuf reuses As, 16KB exactly).
// doCsr: blocks [0,196) run the coarse CSR scatter.
__global__ __launch_bounds__(512, 8)
void gemm_xrs(const unsigned char* __restrict__ A,
              const unsigned char* __restrict__ Wt,
              unsigned char* __restrict__ xrs, int doCsr,
              const int* __restrict__ src, const int* __restrict__ dst,
              const int* __restrict__ et, int* __restrict__ bcur,
              int* __restrict__ ebuf) {
  __shared__ uint4 As[1024];  // 128 rows x 8 uint4 (fp8), xor-swizzled
  __shared__ uint4 Bs[1024];
  __shared__ int lhist[NBKT];
  __shared__ int lbase[NBKT];
  const int tid = threadIdx.x;

  if (doCsr && blockIdx.x < CSR_BLOCKS) {
    // ---- coarse scatter: record = (dst_local<<19)|(src<<3)|et ----
    if (tid < NBKT) lhist[tid] = 0;
    __syncthreads();
    int e0 = blockIdx.x * 4096;
    int rec[8], cc[8], lr[8];
#pragma unroll
    for (int i = 0; i < 8; ++i) {
      int e = e0 + tid + i * 512;
      if (e < NEDGES) {
        int d = dst[e];
        cc[i] = d >> BSH;
        rec[i] = ((d & 511) << 19) | (src[e] << 3) | et[e];
        lr[i] = atomicAdd(&lhist[cc[i]], 1);
      } else {
        cc[i] = -1;
      }
    }
    __syncthreads();
    if (tid < NBKT && lhist[tid] > 0) lbase[tid] = atomicAdd(&bcur[tid], lhist[tid]);
    __syncthreads();
#pragma unroll
    for (int i = 0; i < 8; ++i)
      if (cc[i] >= 0) ebuf[cc[i] * SEG + lbase[cc[i]] + lr[i]] = rec[i];
    return;
  }

  const int id = blockIdx.x - (doCsr ? CSR_BLOCKS : 0);
  const int x = id & 7, j = id >> 3;
  const int tile = (j / 9) * 8 + x;
  const int cb = j % 9;
  if (tile >= NTILES) return;
  const int row0 = tile * 128;

  const int lane = tid & 63;
  const int w = tid >> 6;           // 0..7
  const int i16 = lane & 15, q = lane >> 4;
  const int mbase = (w & 3) * 32, nbase = (w >> 2) * 64;

  // Stage fp8 tiles via global_load_lds: slot L (r=L>>3, chunk c8s=L&7)
  // receives source chunk c8s ^ (r&7)  (involution matches the read side).
#pragma unroll
  for (int i = 0; i < 2; ++i) {
    int L = tid + i * 512;
    int r = L >> 3, c8s = L & 7;
    int c8 = c8s ^ (r & 7);
    int agr = row0 + r; if (agr >= NNODES) agr = NNODES - 1;
    gll16((const void*)(A + (size_t)agr * F + c8 * 16), (void*)&As[L]);
    gll16((const void*)(Wt + ((size_t)cb * 128 + r) * F + c8 * 16), (void*)&Bs[L]);
  }
  __syncthreads();

  f32x4 acc[2][4];
#pragma unroll
  for (int a = 0; a < 2; ++a)
#pragma unroll
    for (int b = 0; b < 4; ++b) acc[a][b] = (f32x4)0.f;

  const char* Ab = (const char*)As;
  const char* Bb = (const char*)Bs;
#pragma unroll
  for (int c = 0; c < 4; ++c) {
    // lane holds 8 fp8 K-elems: k = c*32 + q*8 .. +7
    const int ch = c * 2 + (q >> 1);   // 16B chunk index of that K-slice
    const int h8 = (q & 1) << 3;       // 8B half within chunk
    long af[2], bfr[4];
#pragma unroll
    for (int mi = 0; mi < 2; ++mi) {
      int r = mbase + mi * 16 + i16;
      af[mi] = *(const long*)(Ab + r * 128 + ((ch ^ (r & 7)) << 4) + h8);
    }
#pragma unroll
    for (int ni = 0; ni < 4; ++ni) {
      int r = nbase + ni * 16 + i16;
      bfr[ni] = *(const long*)(Bb + r * 128 + ((ch ^ (r & 7)) << 4) + h8);
    }
    // Swapped operands: D[m=weight feature][n=node row]
#pragma unroll
    for (int mi = 0; mi < 2; ++mi)
#pragma unroll
      for (int ni = 0; ni < 4; ++ni)
        acc[mi][ni] = __builtin_amdgcn_mfma_f32_16x16x32_fp8_fp8(
            bfr[ni], af[mi], acc[mi][ni], 0, 0, 0);
  }

  // ---- Epilogue with LDS transpose (R16) ----
  // Pack fp8 dwords, stage into swizzled sbuf[nl][32], then store
  // cooperatively: 8 lanes x 16B = one node's contiguous 128B slice.
  unsigned pkv[2][4];
#pragma unroll
  for (int mi = 0; mi < 2; ++mi)
#pragma unroll
    for (int ni = 0; ni < 4; ++ni) {
      f32x4 v = acc[mi][ni];
      unsigned pk = 0;
      pk = __builtin_amdgcn_cvt_pk_fp8_f32(v[0], v[1], pk, false);
      pk = __builtin_amdgcn_cvt_pk_fp8_f32(v[2], v[3], pk, true);
      pkv[mi][ni] = pk;
    }

  __syncthreads();  // all waves done reading As; reuse As as staging (16KB)
  unsigned* sbuf = (unsigned*)As;  // [128 nodes][32 dwords] = 16KB
  {
    const int dbase = (nbase >> 2) + q;
#pragma unroll
    for (int mi = 0; mi < 2; ++mi) {
      int nl = mbase + mi * 16 + i16;
      int sw = (nl & 7) << 2;
      int vb_ = nl * 32;
#pragma unroll
      for (int ni = 0; ni < 4; ++ni)
        sbuf[vb_ + ((dbase + ni * 4) ^ sw)] = pkv[mi][ni];
    }
  }
  __syncthreads();

#pragma unroll
  for (int k = 0; k < 2; ++k) {
    int nl = k * 64 + (tid >> 3);
    int ch = tid & 7;
    int d0 = (ch * 4) ^ ((nl & 7) << 2);
    uint4 v = *(const uint4*)&sbuf[nl * 32 + d0];
    int row = row0 + nl;
    if (row < NNODES)
      *(uint4*)(xrs + (size_t)row * NOUT + cb * 128 + ch * 16) = v;
  }
}

// ========== aggregate: h_next[dst] = relu(sum_e xrs[edata] + self + b) ======
// Paired-edge: half-wave (32 lanes) per edge, 4B dword loads, 8 pairs in
// flight, __shfl for offsets, __shfl_xor(32) merges halves. 12500 blocks x
// 4 nodes = 50000 exactly. hout != null: store fp8 h (R20). pooled_p !=
// null: LDS-reduce block's 4 nodes, atomicAdd into 64-slot-spread partials.
__global__ __launch_bounds__(256)
void k_aggregate(const unsigned char* __restrict__ xrs,
                 const int* __restrict__ rowptr, const int* __restrict__ edata,
                 const float* __restrict__ bias, unsigned char* __restrict__ hout,
                 float* __restrict__ pooled_p) {
  __shared__ float red[4][128];
  const int wv = threadIdx.x >> 6;
  const int node = blockIdx.x * 4 + wv;
  const int lane = threadIdx.x & 63;
  const int half = lane >> 5, sl = lane & 31;
  const int beg = rowptr[node], end = rowptr[node + 1];

  float a0 = 0.f, a1 = 0.f, a2 = 0.f, a3 = 0.f;
  // self-loop row (r=8), counted once by half 0
  if (half == 0) {
    unsigned sv = *(const unsigned*)(xrs + (size_t)node * NOUT + NREL * F + sl * 4);
    f32x2 lo = __builtin_amdgcn_cvt_pk_f32_fp8(sv, false);
    f32x2 hi = __builtin_amdgcn_cvt_pk_f32_fp8(sv, true);
    a0 += lo[0]; a1 += lo[1]; a2 += hi[0]; a3 += hi[1];
  }

  for (int base = beg; base < end; base += 64) {
    int cnt = end - base; if (cnt > 64) cnt = 64;
    int my = (base + lane < end) ? edata[base + lane] : 0;
    int pairs = cnt >> 1;
    int p = 0;
    for (; p + 8 <= pairs; p += 8) {
      unsigned v[8];
#pragma unroll
      for (int k = 0; k < 8; ++k) {
        int off = __shfl(my, 2 * (p + k) + half, 64);
        v[k] = *(const unsigned*)(xrs + (size_t)off + sl * 4);
      }
#pragma unroll
      for (int k = 0; k < 8; ++k) {
        f32x2 lo = __builtin_amdgcn_cvt_pk_f32_fp8(v[k], false);
        f32x2 hi = __builtin_amdgcn_cvt_pk_f32_fp8(v[k], true);
        a0 += lo[0]; a1 += lo[1]; a2 += hi[0]; a3 += hi[1];
      }
    }
    for (; p < pairs; ++p) {
      int off = __shfl(my, 2 * p + half, 64);
      unsigned vv = *(const unsigned*)(xrs + (size_t)off + sl * 4);
      f32x2 lo = __builtin_amdgcn_cvt_pk_f32_fp8(vv, false);
      f32x2 hi = __builtin_amdgcn_cvt_pk_f32_fp8(vv, true);
      a0 += lo[0]; a1 += lo[1]; a2 += hi[0]; a3 += hi[1];
    }
    if (cnt & 1) {
      int off = __shfl(my, cnt - 1, 64);
      if (half == 0) {
        unsigned vv = *(const unsigned*)(xrs + (size_t)off + sl * 4);
        f32x2 lo = __builtin_amdgcn_cvt_pk_f32_fp8(vv, false);
        f32x2 hi = __builtin_amdgcn_cvt_pk_f32_fp8(vv, true);
        a0 += lo[0]; a1 += lo[1]; a2 += hi[0]; a3 += hi[1];
      }
    }
  }

  // merge the two half-wave partial sums
  a0 += __shfl_xor(a0, 32, 64);
  a1 += __shfl_xor(a1, 32, 64);
  a2 += __shfl_xor(a2, 32, 64);
  a3 += __shfl_xor(a3, 32, 64);

  float4 bb = ((const float4*)bias)[sl];
  a0 = fmaxf(a0 + bb.x, 0.f);
  a1 = fmaxf(a1 + bb.y, 0.f);
  a2 = fmaxf(a2 + bb.z, 0.f);
  a3 = fmaxf(a3 + bb.w, 0.f);

  if (hout) {
    if (half == 0) {
      unsigned pk = 0;
      pk = __builtin_amdgcn_cvt_pk_fp8_f32(a0, a1, pk, false);
      pk = __builtin_amdgcn_cvt_pk_fp8_f32(a2, a3, pk, true);
      ((unsigned*)(hout + (size_t)node * F))[sl] = pk;
    }
  } else {
    if (half == 0) {
      red[wv][sl * 4 + 0] = a0;
      red[wv][sl * 4 + 1] = a1;
      red[wv][sl * 4 + 2] = a2;
      red[wv][sl * 4 + 3] = a3;
    }
    __syncthreads();
    if (threadIdx.x < 128) {
      float s = red[0][threadIdx.x] + red[1][threadIdx.x] +
                red[2][threadIdx.x] + red[3][threadIdx.x];
      atomicAdd(&pooled_p[(blockIdx.x & 63) * 128 + threadIdx.x], s);
    }
  }
}

// ================== final: reduce 64x128 partials + fc + sigmoid ============
__global__ __launch_bounds__(128)
void k_final(const float* __restrict__ pooled_p, const float* __restrict__ fcw,
             const float* __restrict__ fcb, float* __restrict__ out) {
  __shared__ float s[128];
  int t = threadIdx.x;
  float acc = 0.f;
#pragma unroll 8
  for (int k = 0; k < 64; ++k) acc += pooled_p[k * 128 + t];
  s[t] = acc * (1.0f / (float)NNODES) * fcw[t];
  __syncthreads();
  if (t == 0) {
    float v = 0.f;
    for (int i = 0; i < 128; ++i) v += s[i];
    v += fcb[0];
    out[0] = 1.f / (1.f + expf(-v));
  }
}

// ============================================================================
extern "C" void kernel_launch(void* const* d_in, const int* in_sizes, int n_in,
                              void* d_out, int out_size, void* d_ws, size_t ws_size,
                              hipStream_t stream) {
  const float* in_feat = (const float*)d_in[0];
  const float* W1      = (const float*)d_in[1];
  const float* W1s     = (const float*)d_in[2];
  const float* b1      = (const float*)d_in[3];
  const float* W2      = (const float*)d_in[4];
  const float* W2s     = (const float*)d_in[5];
  const float* b2      = (const float*)d_in[6];
  const float* fcw     = (const float*)d_in[7];
  const float* fcb     = (const float*)d_in[8];
  const int*   src     = (const int*)d_in[9];
  const int*   dst     = (const int*)d_in[10];
  const int*   et      = (const int*)d_in[11];
  float* out = (float*)d_out;

  // Workspace (~80 MB)
  unsigned char* xrs = (unsigned char*)d_ws;              // [50000][1152] fp8
  unsigned char* feat0 = xrs + (size_t)NNODES * NOUT;     // [50000][128] fp8
  unsigned char* h1  = feat0 + (size_t)NNODES * F;        // [50000][128] fp8
  unsigned char* Wt1 = h1 + (size_t)NNODES * F;           // [1152][128] fp8
  unsigned char* Wt2 = Wt1 + (size_t)NOUT * F;            // [1152][128] fp8
  float* pooled_p = (float*)(Wt2 + (size_t)NOUT * F);     // [64][128]
  int*   bcur   = (int*)(pooled_p + 64 * 128);            // [NBKT+1]
  int*   rowptr = bcur + NBKT + 1;                        // [NNODES+1]
  int*   ebuf   = rowptr + NNODES + 2;                    // [NBKT*SEG]
  int*   edata  = ebuf + NBKT * SEG;                      // [NEDGES]

  // fused prep: zero(pooled_p,bcur) | feat cvt fp8 | weight prep x2
  k_prep<<<PREP_ZERO + PREP_CVT + 2 * PREP_W, 256, 0, stream>>>(
      in_feat, (unsigned*)feat0, W1, W1s, (unsigned*)Wt1,
      W2, W2s, (unsigned*)Wt2, pooled_p, bcur);

  const int aggBlocks = NNODES / 4;                    // 12500

  // Layer 1 GEMM with CSR-scatter fused (scatter hidden under GEMM)
  gemm_xrs<<<CSR_BLOCKS + GEMM_BLOCKS, 512, 0, stream>>>(
      feat0, Wt1, xrs, 1, src, dst, et, bcur, ebuf);
  k_fsort<<<NBKT, 256, 0, stream>>>(ebuf, bcur, rowptr, edata);
  k_aggregate<<<aggBlocks, 256, 0, stream>>>(xrs, rowptr, edata, b1, h1, nullptr);
  // Layer 2 (pooling fused into aggregate; h2 never materialized)
  gemm_xrs<<<GEMM_BLOCKS, 512, 0, stream>>>(
      h1, Wt2, xrs, 0, src, dst, et, bcur, ebuf);
  k_aggregate<<<aggBlocks, 256, 0, stream>>>(xrs, rowptr, edata, b2, nullptr, pooled_p);

  // Reduce partials + fc + sigmoid
  k_final<<<1, 128, 0, stream>>>(pooled_p, fcw, fcb, out);
}

// Round 7
// 211.282 us; speedup vs baseline: 5.4444x; 1.0416x over previous
//
#include <hip/hip_runtime.h>

#define NNODES 50000
#define NEDGES 800000
#define F 128
#define NREL 8
#define NOUT 1152   // 9*128: 8 relations + self-loop
#define NBKT 98     // ceil(50000 / 512) coarse buckets
#define BSH 9       // 512 nodes per bucket
#define SEG 16384   // fixed ebuf segment per bucket (max bucket ~8.5k)
#define NTILES 391  // ceil(50000/128)
#define GEMM_BLOCKS (8 * 9 * 49)   // 3528 (XCD-swizzled)
#define CSR_BLOCKS 196

typedef float f32x4 __attribute__((ext_vector_type(4)));
typedef float f32x2 __attribute__((ext_vector_type(2)));

__device__ __forceinline__ unsigned f2bf(float f) {  // RNE
  unsigned u = __float_as_uint(f);
  u += 0x7fffu + ((u >> 16) & 1u);
  return u >> 16;
}

typedef __attribute__((address_space(3))) void lds_void;
typedef const __attribute__((address_space(1))) void glb_void;
__device__ __forceinline__ void gll16(const void* g, void* l) {
  // async global->LDS, 16B per lane; LDS dest = wave-uniform base + lane*16
  __builtin_amdgcn_global_load_lds(
      (glb_void*)(unsigned long long)g,
      (lds_void*)(unsigned)(unsigned long long)l, 16, 0, 0);
}

// ========== fused prep: zero | cvt(fp8) | prepw(W1) | prepw(W2) =============
// R20: feat0 and Wt are fp8 e4m3 (GEMM datapath fp8 end-to-end).
#define PREP_ZERO  33
#define PREP_CVT   6250    // 50000*128/4 / 256 uints
#define PREP_W     144     // 1152*128/4 / 256 uints per weight set
__global__ __launch_bounds__(256)
void k_prep(const float* __restrict__ in_feat, unsigned* __restrict__ feat0,
            const float* __restrict__ W1, const float* __restrict__ W1s,
            unsigned* __restrict__ Wt1,
            const float* __restrict__ W2, const float* __restrict__ W2s,
            unsigned* __restrict__ Wt2,
            float* __restrict__ pooled_p, int* __restrict__ bcur) {
  const int b = blockIdx.x, t = threadIdx.x;
  if (b < 32) {
    pooled_p[b * 256 + t] = 0.f;          // 32*256 = 8192 = 64*128
  } else if (b < PREP_ZERO) {
    if (t <= NBKT) bcur[t] = 0;           // bcur[98] (+1 spare)
  } else if (b < PREP_ZERO + PREP_CVT) {
    int i = (b - PREP_ZERO) * 256 + t;    // exactly 1.6M float4 -> uint
    float4 v = ((const float4*)in_feat)[i];
    unsigned pk = 0;
    pk = __builtin_amdgcn_cvt_pk_fp8_f32(v.x, v.y, pk, false);
    pk = __builtin_amdgcn_cvt_pk_fp8_f32(v.z, v.w, pk, true);
    feat0[i] = pk;
  } else {
    int w2 = (b >= PREP_ZERO + PREP_CVT + PREP_W);
    int idx = (b - PREP_ZERO - PREP_CVT - (w2 ? PREP_W : 0)) * 256 + t;
    int n = idx >> 5, k0 = (idx & 31) * 4;   // Wt[n][k0..k0+3]
    int r = n >> 7, c = n & 127;
    const float* Wr = w2 ? W2 : W1;
    const float* Ws = w2 ? W2s : W1s;
    float v0, v1, v2, v3;
    if (r < NREL) {
      v0 = Wr[((size_t)(r * F + k0 + 0)) * F + c];
      v1 = Wr[((size_t)(r * F + k0 + 1)) * F + c];
      v2 = Wr[((size_t)(r * F + k0 + 2)) * F + c];
      v3 = Wr[((size_t)(r * F + k0 + 3)) * F + c];
    } else {
      v0 = Ws[(size_t)(k0 + 0) * F + c];
      v1 = Ws[(size_t)(k0 + 1) * F + c];
      v2 = Ws[(size_t)(k0 + 2) * F + c];
      v3 = Ws[(size_t)(k0 + 3) * F + c];
    }
    unsigned pk = 0;
    pk = __builtin_amdgcn_cvt_pk_fp8_f32(v0, v1, pk, false);
    pk = __builtin_amdgcn_cvt_pk_fp8_f32(v2, v3, pk, true);
    (w2 ? Wt2 : Wt1)[idx] = pk;
  }
}

// ======== fine sort: bucket segment -> CSR (counts from bcur) ===============
// R21: 512 threads/block (grid is only 98 blocks; halve per-block serial work)
__global__ __launch_bounds__(512)
void k_fsort(const int* __restrict__ ebuf, const int* __restrict__ bcur,
             int* __restrict__ rowptr, int* __restrict__ edata) {
  __shared__ int cnt[512];
  __shared__ int pos[512];
  __shared__ int ws2[512];
  __shared__ int bc_s;
  const int b = blockIdx.x, t = threadIdx.x;
  // ---- global base = sum_{k<b} bcur[k] (bcur holds final bucket counts) ----
  int myc = (t < NBKT) ? bcur[t] : 0;
  ws2[t] = (t < b) ? myc : 0;
  if (t == b) bc_s = myc;
  __syncthreads();
  for (int off = 1; off < 512; off <<= 1) {
    int x = (t >= off) ? ws2[t - off] : 0;
    __syncthreads();
    ws2[t] += x;
    __syncthreads();
  }
  const int beg = ws2[511];
  const int cntb = bc_s;
  const int sbeg = b * SEG;  // segment start in ebuf

  cnt[t] = 0;
  __syncthreads();
  for (int e = t; e < cntb; e += 512)
    atomicAdd(&cnt[((unsigned)ebuf[sbeg + e]) >> 19], 1);
  __syncthreads();
  int myn = cnt[t];
  ws2[t] = myn;
  __syncthreads();
  for (int off = 1; off < 512; off <<= 1) {
    int x = (t >= off) ? ws2[t - off] : 0;
    __syncthreads();
    ws2[t] += x;
    __syncthreads();
  }
  pos[t] = ws2[t] - myn;
  __syncthreads();
  int node = (b << BSH) + t;
  if (node < NNODES) rowptr[node] = beg + pos[t];
  if (b == NBKT - 1 && t == 0) rowptr[NNODES] = NEDGES;
  __syncthreads();
  for (int e = t; e < cntb; e += 512) {
    int rec = ebuf[sbeg + e];
    int c = ((unsigned)rec) >> 19;
    int lrank = atomicAdd(&pos[c], 1);
    int srcv = (rec >> 3) & 0xFFFF;
    int etv = rec & 7;
    edata[beg + lrank] = srcv * NOUT + etv * F;  // byte offset in fp8 xrs
  }
}

// ====== GEMM: xrs[50000][1152](fp8) = A[50000][128] @ Wt^T  (fp8 MFMA) ======
// R20: full fp8 datapath. As/Bs 16KB each (LDS 33.5KB -> 4 blocks/CU).
// 8B-granular XOR swizzle; mfma_f32_16x16x32_fp8_fp8, swapped operands.
// Epilogue LDS-transpose stores (R16). doCsr blocks [0,196): CSR scatter.
__global__ __launch_bounds__(512, 8)
void gemm_xrs(const unsigned char* __restrict__ A,
              const unsigned char* __restrict__ Wt,
              unsigned char* __restrict__ xrs, int doCsr,
              const int* __restrict__ src, const int* __restrict__ dst,
              const int* __restrict__ et, int* __restrict__ bcur,
              int* __restrict__ ebuf) {
  __shared__ uint4 As[1024];  // 128 rows x 8 uint4 (fp8), xor-swizzled
  __shared__ uint4 Bs[1024];
  __shared__ int lhist[NBKT];
  __shared__ int lbase[NBKT];
  const int tid = threadIdx.x;

  if (doCsr && blockIdx.x < CSR_BLOCKS) {
    // ---- coarse scatter: record = (dst_local<<19)|(src<<3)|et ----
    if (tid < NBKT) lhist[tid] = 0;
    __syncthreads();
    int e0 = blockIdx.x * 4096;
    int rec[8], cc[8], lr[8];
#pragma unroll
    for (int i = 0; i < 8; ++i) {
      int e = e0 + tid + i * 512;
      if (e < NEDGES) {
        int d = dst[e];
        cc[i] = d >> BSH;
        rec[i] = ((d & 511) << 19) | (src[e] << 3) | et[e];
        lr[i] = atomicAdd(&lhist[cc[i]], 1);
      } else {
        cc[i] = -1;
      }
    }
    __syncthreads();
    if (tid < NBKT && lhist[tid] > 0) lbase[tid] = atomicAdd(&bcur[tid], lhist[tid]);
    __syncthreads();
#pragma unroll
    for (int i = 0; i < 8; ++i)
      if (cc[i] >= 0) ebuf[cc[i] * SEG + lbase[cc[i]] + lr[i]] = rec[i];
    return;
  }

  const int id = blockIdx.x - (doCsr ? CSR_BLOCKS : 0);
  const int x = id & 7, j = id >> 3;
  const int tile = (j / 9) * 8 + x;
  const int cb = j % 9;
  if (tile >= NTILES) return;
  const int row0 = tile * 128;

  const int lane = tid & 63;
  const int w = tid >> 6;           // 0..7
  const int i16 = lane & 15, q = lane >> 4;
  const int mbase = (w & 3) * 32, nbase = (w >> 2) * 64;

  // Stage fp8 tiles via global_load_lds: slot L (r=L>>3, chunk c8s=L&7)
  // receives source chunk c8s ^ (r&7)  (involution matches the read side).
#pragma unroll
  for (int i = 0; i < 2; ++i) {
    int L = tid + i * 512;
    int r = L >> 3, c8s = L & 7;
    int c8 = c8s ^ (r & 7);
    int agr = row0 + r; if (agr >= NNODES) agr = NNODES - 1;
    gll16((const void*)(A + (size_t)agr * F + c8 * 16), (void*)&As[L]);
    gll16((const void*)(Wt + ((size_t)cb * 128 + r) * F + c8 * 16), (void*)&Bs[L]);
  }
  __syncthreads();

  f32x4 acc[2][4];
#pragma unroll
  for (int a = 0; a < 2; ++a)
#pragma unroll
    for (int b = 0; b < 4; ++b) acc[a][b] = (f32x4)0.f;

  const char* Ab = (const char*)As;
  const char* Bb = (const char*)Bs;
#pragma unroll
  for (int c = 0; c < 4; ++c) {
    // lane holds 8 fp8 K-elems: k = c*32 + q*8 .. +7
    const int ch = c * 2 + (q >> 1);   // 16B chunk index of that K-slice
    const int h8 = (q & 1) << 3;       // 8B half within chunk
    long af[2], bfr[4];
#pragma unroll
    for (int mi = 0; mi < 2; ++mi) {
      int r = mbase + mi * 16 + i16;
      af[mi] = *(const long*)(Ab + r * 128 + ((ch ^ (r & 7)) << 4) + h8);
    }
#pragma unroll
    for (int ni = 0; ni < 4; ++ni) {
      int r = nbase + ni * 16 + i16;
      bfr[ni] = *(const long*)(Bb + r * 128 + ((ch ^ (r & 7)) << 4) + h8);
    }
    // Swapped operands: D[m=weight feature][n=node row]
#pragma unroll
    for (int mi = 0; mi < 2; ++mi)
#pragma unroll
      for (int ni = 0; ni < 4; ++ni)
        acc[mi][ni] = __builtin_amdgcn_mfma_f32_16x16x32_fp8_fp8(
            bfr[ni], af[mi], acc[mi][ni], 0, 0, 0);
  }

  // ---- Epilogue with LDS transpose (R16) ----
  unsigned pkv[2][4];
#pragma unroll
  for (int mi = 0; mi < 2; ++mi)
#pragma unroll
    for (int ni = 0; ni < 4; ++ni) {
      f32x4 v = acc[mi][ni];
      unsigned pk = 0;
      pk = __builtin_amdgcn_cvt_pk_fp8_f32(v[0], v[1], pk, false);
      pk = __builtin_amdgcn_cvt_pk_fp8_f32(v[2], v[3], pk, true);
      pkv[mi][ni] = pk;
    }

  __syncthreads();  // all waves done reading As; reuse As as staging (16KB)
  unsigned* sbuf = (unsigned*)As;  // [128 nodes][32 dwords] = 16KB
  {
    const int dbase = (nbase >> 2) + q;
#pragma unroll
    for (int mi = 0; mi < 2; ++mi) {
      int nl = mbase + mi * 16 + i16;
      int sw = (nl & 7) << 2;
      int vb_ = nl * 32;
#pragma unroll
      for (int ni = 0; ni < 4; ++ni)
        sbuf[vb_ + ((dbase + ni * 4) ^ sw)] = pkv[mi][ni];
    }
  }
  __syncthreads();

#pragma unroll
  for (int k = 0; k < 2; ++k) {
    int nl = k * 64 + (tid >> 3);
    int ch = tid & 7;
    int d0 = (ch * 4) ^ ((nl & 7) << 2);
    uint4 v = *(const uint4*)&sbuf[nl * 32 + d0];
    int row = row0 + nl;
    if (row < NNODES)
      *(uint4*)(xrs + (size_t)row * NOUT + cb * 128 + ch * 16) = v;
  }
}

// ========== aggregate: h_next[dst] = relu(sum_e xrs[edata] + self + b) ======
// R21: quad-edge groups. 16 lanes x uint2 (8B) per edge -> one wave-instr
// covers 4 edges (was 2 w/ dword); 8 loads in flight = 32 edges deep.
// Lane (g=lane>>4, s=lane&15) accumulates feats s*8..s*8+7 for edges
// e==g (mod 4); merge groups via shfl_xor 32 then 16. 12500 blocks x 4
// nodes. hout: fp8 h store (uint2/row by g==0). pooled_p: LDS-reduce +
// 64-slot-spread atomics.
__global__ __launch_bounds__(256)
void k_aggregate(const unsigned char* __restrict__ xrs,
                 const int* __restrict__ rowptr, const int* __restrict__ edata,
                 const float* __restrict__ bias, unsigned char* __restrict__ hout,
                 float* __restrict__ pooled_p) {
  __shared__ float red[4][128];
  const int wv = threadIdx.x >> 6;
  const int node = blockIdx.x * 4 + wv;
  const int lane = threadIdx.x & 63;
  const int g = lane >> 4, s = lane & 15;
  const int beg = rowptr[node], end = rowptr[node + 1];

  float a[8];
#pragma unroll
  for (int j = 0; j < 8; ++j) a[j] = 0.f;

  // self-loop row (r=8), counted once by group 0
  if (g == 0) {
    uint2 sv = *(const uint2*)(xrs + (size_t)node * NOUT + NREL * F + s * 8);
    f32x2 l0 = __builtin_amdgcn_cvt_pk_f32_fp8(sv.x, false);
    f32x2 h0 = __builtin_amdgcn_cvt_pk_f32_fp8(sv.x, true);
    f32x2 l1 = __builtin_amdgcn_cvt_pk_f32_fp8(sv.y, false);
    f32x2 h1 = __builtin_amdgcn_cvt_pk_f32_fp8(sv.y, true);
    a[0] += l0[0]; a[1] += l0[1]; a[2] += h0[0]; a[3] += h0[1];
    a[4] += l1[0]; a[5] += l1[1]; a[6] += h1[0]; a[7] += h1[1];
  }

  for (int base = beg; base < end; base += 64) {
    int cnt = end - base; if (cnt > 64) cnt = 64;
    int my = (base + lane < end) ? edata[base + lane] : 0;
    int nfull = cnt >> 2, tail = cnt & 3;
    for (int qb = 0; qb < nfull; qb += 8) {
      int nq = nfull - qb; if (nq > 8) nq = 8;
      uint2 v[8];
#pragma unroll
      for (int k = 0; k < 8; ++k) {
        if (k < nq) {
          int off = __shfl(my, 4 * (qb + k) + g, 64);
          v[k] = *(const uint2*)(xrs + (size_t)off + s * 8);
        }
      }
#pragma unroll
      for (int k = 0; k < 8; ++k) {
        if (k < nq) {
          f32x2 l0 = __builtin_amdgcn_cvt_pk_f32_fp8(v[k].x, false);
          f32x2 h0 = __builtin_amdgcn_cvt_pk_f32_fp8(v[k].x, true);
          f32x2 l1 = __builtin_amdgcn_cvt_pk_f32_fp8(v[k].y, false);
          f32x2 h1 = __builtin_amdgcn_cvt_pk_f32_fp8(v[k].y, true);
          a[0] += l0[0]; a[1] += l0[1]; a[2] += h0[0]; a[3] += h0[1];
          a[4] += l1[0]; a[5] += l1[1]; a[6] += h1[0]; a[7] += h1[1];
        }
      }
    }
    if (tail) {
      int e = 4 * nfull + g;
      int off = __shfl(my, (e < cnt) ? e : 0, 64);
      if (g < tail) {
        uint2 vv = *(const uint2*)(xrs + (size_t)off + s * 8);
        f32x2 l0 = __builtin_amdgcn_cvt_pk_f32_fp8(vv.x, false);
        f32x2 h0 = __builtin_amdgcn_cvt_pk_f32_fp8(vv.x, true);
        f32x2 l1 = __builtin_amdgcn_cvt_pk_f32_fp8(vv.y, false);
        f32x2 h1 = __builtin_amdgcn_cvt_pk_f32_fp8(vv.y, true);
        a[0] += l0[0]; a[1] += l0[1]; a[2] += h0[0]; a[3] += h0[1];
        a[4] += l1[0]; a[5] += l1[1]; a[6] += h1[0]; a[7] += h1[1];
      }
    }
  }

  // merge the four group partial sums (g0..g3 hold edges e%4==g)
#pragma unroll
  for (int j = 0; j < 8; ++j) {
    a[j] += __shfl_xor(a[j], 32, 64);
    a[j] += __shfl_xor(a[j], 16, 64);
  }

  float4 bb0 = ((const float4*)bias)[s * 2];
  float4 bb1 = ((const float4*)bias)[s * 2 + 1];
  a[0] = fmaxf(a[0] + bb0.x, 0.f);
  a[1] = fmaxf(a[1] + bb0.y, 0.f);
  a[2] = fmaxf(a[2] + bb0.z, 0.f);
  a[3] = fmaxf(a[3] + bb0.w, 0.f);
  a[4] = fmaxf(a[4] + bb1.x, 0.f);
  a[5] = fmaxf(a[5] + bb1.y, 0.f);
  a[6] = fmaxf(a[6] + bb1.z, 0.f);
  a[7] = fmaxf(a[7] + bb1.w, 0.f);

  if (hout) {
    if (g == 0) {
      uint2 pk;
      unsigned p0 = 0;
      p0 = __builtin_amdgcn_cvt_pk_fp8_f32(a[0], a[1], p0, false);
      p0 = __builtin_amdgcn_cvt_pk_fp8_f32(a[2], a[3], p0, true);
      unsigned p1 = 0;
      p1 = __builtin_amdgcn_cvt_pk_fp8_f32(a[4], a[5], p1, false);
      p1 = __builtin_amdgcn_cvt_pk_fp8_f32(a[6], a[7], p1, true);
      pk.x = p0; pk.y = p1;
      ((uint2*)(hout + (size_t)node * F))[s] = pk;
    }
  } else {
    if (g == 0) {
#pragma unroll
      for (int j = 0; j < 8; ++j) red[wv][s * 8 + j] = a[j];
    }
    __syncthreads();
    if (threadIdx.x < 128) {
      float sm = red[0][threadIdx.x] + red[1][threadIdx.x] +
                 red[2][threadIdx.x] + red[3][threadIdx.x];
      atomicAdd(&pooled_p[(blockIdx.x & 63) * 128 + threadIdx.x], sm);
    }
  }
}

// ================== final: reduce 64x128 partials + fc + sigmoid ============
__global__ __launch_bounds__(128)
void k_final(const float* __restrict__ pooled_p, const float* __restrict__ fcw,
             const float* __restrict__ fcb, float* __restrict__ out) {
  __shared__ float s[128];
  int t = threadIdx.x;
  float acc = 0.f;
#pragma unroll 8
  for (int k = 0; k < 64; ++k) acc += pooled_p[k * 128 + t];
  s[t] = acc * (1.0f / (float)NNODES) * fcw[t];
  __syncthreads();
  if (t == 0) {
    float v = 0.f;
    for (int i = 0; i < 128; ++i) v += s[i];
    v += fcb[0];
    out[0] = 1.f / (1.f + expf(-v));
  }
}

// ============================================================================
extern "C" void kernel_launch(void* const* d_in, const int* in_sizes, int n_in,
                              void* d_out, int out_size, void* d_ws, size_t ws_size,
                              hipStream_t stream) {
  const float* in_feat = (const float*)d_in[0];
  const float* W1      = (const float*)d_in[1];
  const float* W1s     = (const float*)d_in[2];
  const float* b1      = (const float*)d_in[3];
  const float* W2      = (const float*)d_in[4];
  const float* W2s     = (const float*)d_in[5];
  const float* b2      = (const float*)d_in[6];
  const float* fcw     = (const float*)d_in[7];
  const float* fcb     = (const float*)d_in[8];
  const int*   src     = (const int*)d_in[9];
  const int*   dst     = (const int*)d_in[10];
  const int*   et      = (const int*)d_in[11];
  float* out = (float*)d_out;

  // Workspace (~80 MB)
  unsigned char* xrs = (unsigned char*)d_ws;              // [50000][1152] fp8
  unsigned char* feat0 = xrs + (size_t)NNODES * NOUT;     // [50000][128] fp8
  unsigned char* h1  = feat0 + (size_t)NNODES * F;        // [50000][128] fp8
  unsigned char* Wt1 = h1 + (size_t)NNODES * F;           // [1152][128] fp8
  unsigned char* Wt2 = Wt1 + (size_t)NOUT * F;            // [1152][128] fp8
  float* pooled_p = (float*)(Wt2 + (size_t)NOUT * F);     // [64][128]
  int*   bcur   = (int*)(pooled_p + 64 * 128);            // [NBKT+1]
  int*   rowptr = bcur + NBKT + 1;                        // [NNODES+1]
  int*   ebuf   = rowptr + NNODES + 2;                    // [NBKT*SEG]
  int*   edata  = ebuf + NBKT * SEG;                      // [NEDGES]

  // fused prep: zero(pooled_p,bcur) | feat cvt fp8 | weight prep x2
  k_prep<<<PREP_ZERO + PREP_CVT + 2 * PREP_W, 256, 0, stream>>>(
      in_feat, (unsigned*)feat0, W1, W1s, (unsigned*)Wt1,
      W2, W2s, (unsigned*)Wt2, pooled_p, bcur);

  const int aggBlocks = NNODES / 4;                    // 12500

  // Layer 1 GEMM with CSR-scatter fused (scatter hidden under GEMM)
  gemm_xrs<<<CSR_BLOCKS + GEMM_BLOCKS, 512, 0, stream>>>(
      feat0, Wt1, xrs, 1, src, dst, et, bcur, ebuf);
  k_fsort<<<NBKT, 512, 0, stream>>>(ebuf, bcur, rowptr, edata);
  k_aggregate<<<aggBlocks, 256, 0, stream>>>(xrs, rowptr, edata, b1, h1, nullptr);
  // Layer 2 (pooling fused into aggregate; h2 never materialized)
  gemm_xrs<<<GEMM_BLOCKS, 512, 0, stream>>>(
      h1, Wt2, xrs, 0, src, dst, et, bcur, ebuf);
  k_aggregate<<<aggBlocks, 256, 0, stream>>>(xrs, rowptr, edata, b2, nullptr, pooled_p);

  // Reduce partials + fc + sigmoid
  k_final<<<1, 128, 0, stream>>>(pooled_p, fcw, fcb, out);
}